// Round 1
// baseline (83.048 us; speedup 1.0000x reference)
//
#include <hip/hip_runtime.h>
#include <hip/hip_bf16.h>
#include <cstdint>
#include <cstddef>

#define NB 4096     // batch rows
#define NC 1000     // real classes
#define NCP 1024    // padded classes
#define ND 3072     // feature dim

typedef __attribute__((ext_vector_type(8))) __bf16 bf16x8;
typedef __attribute__((ext_vector_type(4))) float f32x4;
typedef __attribute__((ext_vector_type(4))) unsigned short u16x4;
typedef unsigned short u16;

__device__ __forceinline__ u16 f2bf_rne(float x) {
    uint32_t u = __float_as_uint(x);
    uint32_t r = (u + 0x7fffu + ((u >> 16) & 1u)) >> 16;
    return (u16)r;
}

// ---------------------------------------------------------------------------
// Convert f32 rows -> bf16 rows, computing per-row sum of squares (in f32).
// Rows >= nrows_src are zero-padded with sq = pad_sq (used to kill padded
// classes in the logsumexp: dists_pad = -0.5*(z2 + 1e30) -> exp -> 0).
// ---------------------------------------------------------------------------
__global__ __launch_bounds__(256) void convert_rows_kernel(
        const float* __restrict__ src, u16* __restrict__ dst,
        float* __restrict__ sq, int nrows_src, float pad_sq) {
    const int row = blockIdx.x;
    const int tid = threadIdx.x;
    u16* drow = dst + (size_t)row * ND;
    if (row < nrows_src) {
        const float4* s = (const float4*)(src + (size_t)row * ND);
        float acc = 0.f;
#pragma unroll
        for (int i = 0; i < 3; ++i) {                // 768 float4 / 256 threads
            const int idx = tid + i * 256;
            float4 v = s[idx];
            acc = fmaf(v.x, v.x, acc);
            acc = fmaf(v.y, v.y, acc);
            acc = fmaf(v.z, v.z, acc);
            acc = fmaf(v.w, v.w, acc);
            u16x4 o;
            o.x = f2bf_rne(v.x); o.y = f2bf_rne(v.y);
            o.z = f2bf_rne(v.z); o.w = f2bf_rne(v.w);
            *(u16x4*)(drow + idx * 4) = o;
        }
        // block-wide sum: wave shuffle then 4-slot LDS combine
#pragma unroll
        for (int off = 32; off > 0; off >>= 1) acc += __shfl_xor(acc, off, 64);
        __shared__ float ssum[4];
        const int wid = tid >> 6, lane = tid & 63;
        if (lane == 0) ssum[wid] = acc;
        __syncthreads();
        if (tid == 0) sq[row] = ssum[0] + ssum[1] + ssum[2] + ssum[3];
    } else {
        u16x4 z4 = (u16x4){0, 0, 0, 0};
#pragma unroll
        for (int i = 0; i < 3; ++i) *(u16x4*)(drow + (tid + i * 256) * 4) = z4;
        if (tid == 0) sq[row] = pad_sq;
    }
}

// ---------------------------------------------------------------------------
// dists[b][c] = z_b . mu_c - 0.5*(||z_b||^2 + ||mu_c||^2)
// BM=128 x BN=64 tile, BK=32, 256 threads (4 waves, 2x2), 16x16x32 bf16 MFMA.
// global_load_lds width-16 staging, linear LDS (m97 structure).
// ---------------------------------------------------------------------------
#define BM 128
#define BN 64
#define BK 32

#define GLOAD_LDS16(gp, lp)                                            \
    __builtin_amdgcn_global_load_lds(                                  \
        (const __attribute__((address_space(1))) void*)(gp),           \
        (__attribute__((address_space(3))) void*)(lp), 16, 0, 0)

__global__ __launch_bounds__(256) void gemm_dists_kernel(
        const u16* __restrict__ zb, const u16* __restrict__ mb,
        const float* __restrict__ z2, const float* __restrict__ m2,
        float* __restrict__ dists) {
    __shared__ u16 As[BM * BK];   // 8 KiB, row-major [128][32]
    __shared__ u16 Bs[BN * BK];   // 4 KiB, row-major [64][32] (row = class)

    const int tid  = threadIdx.x;
    const int wid  = tid >> 6;
    const int lane = tid & 63;
    const int wr   = wid >> 1;        // wave row 0..1 (64 rows each)
    const int wc   = wid & 1;         // wave col 0..1 (32 cols each)
    const int lrow = lane & 15;       // fragment row/col index
    const int kgrp = lane >> 4;       // k-group 0..3 -> k offset kgrp*8

    const int brow = blockIdx.y * BM;
    const int bcol = blockIdx.x * BN;

    f32x4 acc[4][2];
#pragma unroll
    for (int m = 0; m < 4; ++m)
#pragma unroll
        for (int n = 0; n < 2; ++n) acc[m][n] = (f32x4){0.f, 0.f, 0.f, 0.f};

    // staging chunk maps: chunk c (16 B) -> row = c>>2, col8 = (c&3)*8
    const int cA0 = (wid * 2 + 0) * 64 + lane;
    const int cA1 = (wid * 2 + 1) * 64 + lane;
    const int cB  = wid * 64 + lane;

    const u16* gA0 = zb + (size_t)(brow + (cA0 >> 2)) * ND + (cA0 & 3) * 8;
    const u16* gA1 = zb + (size_t)(brow + (cA1 >> 2)) * ND + (cA1 & 3) * 8;
    const u16* gB  = mb + (size_t)(bcol + (cB >> 2)) * ND + (cB & 3) * 8;

    // wave-uniform LDS bases (HW writes base + lane*16)
    u16* lA0 = As + (wid * 2 + 0) * 512;
    u16* lA1 = As + (wid * 2 + 1) * 512;
    u16* lB  = Bs + wid * 512;

    for (int k0 = 0; k0 < ND; k0 += BK) {
        __syncthreads();                 // LDS reads of prev iter done
        GLOAD_LDS16(gA0 + k0, lA0);
        GLOAD_LDS16(gA1 + k0, lA1);
        GLOAD_LDS16(gB + k0, lB);
        __syncthreads();                 // staging drained (vmcnt(0) at barrier)

        bf16x8 a[4], b[2];
#pragma unroll
        for (int m = 0; m < 4; ++m)
            a[m] = *(const bf16x8*)&As[(wr * 64 + m * 16 + lrow) * BK + kgrp * 8];
#pragma unroll
        for (int n = 0; n < 2; ++n)
            b[n] = *(const bf16x8*)&Bs[(wc * 32 + n * 16 + lrow) * BK + kgrp * 8];
#pragma unroll
        for (int m = 0; m < 4; ++m)
#pragma unroll
            for (int n = 0; n < 2; ++n)
                acc[m][n] = __builtin_amdgcn_mfma_f32_16x16x32_bf16(
                    a[m], b[n], acc[m][n], 0, 0, 0);
    }

    // epilogue: C/D layout col = lane&15, row = (lane>>4)*4 + r
#pragma unroll
    for (int n = 0; n < 2; ++n) {
        const int gcol = bcol + wc * 32 + n * 16 + lrow;
        const float mhalf = 0.5f * m2[gcol];
#pragma unroll
        for (int m = 0; m < 4; ++m) {
#pragma unroll
            for (int r = 0; r < 4; ++r) {
                const int grow = brow + wr * 64 + m * 16 + kgrp * 4 + r;
                dists[(size_t)grow * NCP + gcol] =
                    acc[m][n][r] - 0.5f * z2[grow] - mhalf;
            }
        }
    }
}

// ---------------------------------------------------------------------------
// Per-row logsumexp + picked: outA[b] = lse - dists[b,label], outB[b] = lse + sldj
// ---------------------------------------------------------------------------
__global__ __launch_bounds__(256) void row_lse_kernel(
        const float* __restrict__ dists, const int* __restrict__ labels,
        const float* __restrict__ sldj, float* __restrict__ outA,
        float* __restrict__ outB) {
    const int row = blockIdx.x;
    const int tid = threadIdx.x;
    const float* dr = dists + (size_t)row * NCP;
    float4 v = ((const float4*)dr)[tid];     // 256 * 4 = 1024 exactly

    float mx = fmaxf(fmaxf(v.x, v.y), fmaxf(v.z, v.w));
#pragma unroll
    for (int off = 32; off > 0; off >>= 1) mx = fmaxf(mx, __shfl_xor(mx, off, 64));
    __shared__ float smax[4], ssum[4];
    const int wid = tid >> 6, lane = tid & 63;
    if (lane == 0) smax[wid] = mx;
    __syncthreads();
    const float bm = fmaxf(fmaxf(smax[0], smax[1]), fmaxf(smax[2], smax[3]));

    float s = expf(v.x - bm) + expf(v.y - bm) + expf(v.z - bm) + expf(v.w - bm);
#pragma unroll
    for (int off = 32; off > 0; off >>= 1) s += __shfl_xor(s, off, 64);
    if (lane == 0) ssum[wid] = s;
    __syncthreads();
    if (tid == 0) {
        const float tot = ssum[0] + ssum[1] + ssum[2] + ssum[3];
        const float lpz = bm + logf(tot);
        const float picked = dr[labels[row]];
        outA[row] = lpz - picked;
        outB[row] = lpz + sldj[row];
    }
}

// ---------------------------------------------------------------------------
// Deterministic final reduction (single block, fixed tree order).
// ---------------------------------------------------------------------------
__global__ __launch_bounds__(1024) void finalize_kernel(
        const float* __restrict__ a, const float* __restrict__ b,
        const float* __restrict__ beta, float* __restrict__ out) {
    __shared__ float sa[1024], sb[1024];
    const int tid = threadIdx.x;
    float va = 0.f, vb = 0.f;
    for (int i = tid; i < NB; i += 1024) { va += a[i]; vb += b[i]; }
    sa[tid] = va; sb[tid] = vb;
    __syncthreads();
    for (int s = 512; s > 0; s >>= 1) {
        if (tid < s) { sa[tid] += sa[tid + s]; sb[tid] += sb[tid + s]; }
        __syncthreads();
    }
    if (tid == 0) {
        const float loss_cls = sa[0] / (float)NB;
        const float loss_gen = -(sb[0] / (float)NB) / (float)ND;
        const float total = loss_gen + beta[0] * loss_cls;
        out[0] = total;
        out[1] = loss_gen;
        out[2] = loss_cls;
    }
}

extern "C" void kernel_launch(void* const* d_in, const int* in_sizes, int n_in,
                              void* d_out, int out_size, void* d_ws, size_t ws_size,
                              hipStream_t stream) {
    const float* z      = (const float*)d_in[0];
    const float* sldj   = (const float*)d_in[1];
    const int*   labels = (const int*)d_in[2];
    const float* beta   = (const float*)d_in[3];
    const float* means  = (const float*)d_in[4];
    float* out = (float*)d_out;

    char* ws = (char*)d_ws;
    size_t off = 0;
    u16* zb = (u16*)(ws + off);      off += (size_t)NB * ND * 2;    // 25.2 MB
    u16* mb = (u16*)(ws + off);      off += (size_t)NCP * ND * 2;   //  6.3 MB
    float* z2 = (float*)(ws + off);  off += (size_t)NB * 4;
    float* m2 = (float*)(ws + off);  off += (size_t)NCP * 4;
    float* dists = (float*)(ws + off); off += (size_t)NB * NCP * 4; // 16.8 MB
    float* ra = (float*)(ws + off);  off += (size_t)NB * 4;
    float* rb = (float*)(ws + off);  off += (size_t)NB * 4;

    convert_rows_kernel<<<NB, 256, 0, stream>>>(z, zb, z2, NB, 0.f);
    convert_rows_kernel<<<NCP, 256, 0, stream>>>(means, mb, m2, NC, 1e30f);
    gemm_dists_kernel<<<dim3(NCP / BN, NB / BM), 256, 0, stream>>>(zb, mb, z2, m2, dists);
    row_lse_kernel<<<NB, 256, 0, stream>>>(dists, labels, sldj, ra, rb);
    finalize_kernel<<<1, 1024, 0, stream>>>(ra, rb, beta, out);
}

// Round 2
// 68.510 us; speedup vs baseline: 1.2122x; 1.2122x over previous
//
#include <hip/hip_runtime.h>
#include <hip/hip_bf16.h>
#include <cstdint>
#include <cstddef>

#define NB 4096     // batch rows
#define NC 1000     // real classes
#define NCP 1024    // padded classes
#define ND 3072     // feature dim

typedef __attribute__((ext_vector_type(8))) __bf16 bf16x8;
typedef __attribute__((ext_vector_type(4))) float f32x4;
typedef __attribute__((ext_vector_type(4))) unsigned short u16x4;
typedef unsigned short u16;

__device__ __forceinline__ u16 f2bf_rne(float x) {
    uint32_t u = __float_as_uint(x);
    uint32_t r = (u + 0x7fffu + ((u >> 16) & 1u)) >> 16;
    return (u16)r;
}

// ---------------------------------------------------------------------------
// Convert f32 rows -> bf16 rows, computing per-row sum of squares (in f32).
// Rows >= nrows_src are zero-padded with sq = pad_sq (kills padded classes in
// the logsumexp: dists_pad = -0.5*(z2 + 1e30) -> exp -> 0).
// ---------------------------------------------------------------------------
__global__ __launch_bounds__(256) void convert_rows_kernel(
        const float* __restrict__ src, u16* __restrict__ dst,
        float* __restrict__ sq, int nrows_src, float pad_sq) {
    const int row = blockIdx.x;
    const int tid = threadIdx.x;
    u16* drow = dst + (size_t)row * ND;
    if (row < nrows_src) {
        const float4* s = (const float4*)(src + (size_t)row * ND);
        float acc = 0.f;
#pragma unroll
        for (int i = 0; i < 3; ++i) {                // 768 float4 / 256 threads
            const int idx = tid + i * 256;
            float4 v = s[idx];
            acc = fmaf(v.x, v.x, acc);
            acc = fmaf(v.y, v.y, acc);
            acc = fmaf(v.z, v.z, acc);
            acc = fmaf(v.w, v.w, acc);
            u16x4 o;
            o.x = f2bf_rne(v.x); o.y = f2bf_rne(v.y);
            o.z = f2bf_rne(v.z); o.w = f2bf_rne(v.w);
            *(u16x4*)(drow + idx * 4) = o;
        }
#pragma unroll
        for (int off = 32; off > 0; off >>= 1) acc += __shfl_xor(acc, off, 64);
        __shared__ float ssum[4];
        const int wid = tid >> 6, lane = tid & 63;
        if (lane == 0) ssum[wid] = acc;
        __syncthreads();
        if (tid == 0) sq[row] = ssum[0] + ssum[1] + ssum[2] + ssum[3];
    } else {
        u16x4 z4 = (u16x4){0, 0, 0, 0};
#pragma unroll
        for (int i = 0; i < 3; ++i) *(u16x4*)(drow + (tid + i * 256) * 4) = z4;
        if (tid == 0) sq[row] = pad_sq;
    }
}

// ---------------------------------------------------------------------------
// dists[b][c] = z_b . mu_c - 0.5*(||z_b||^2 + ||mu_c||^2)
// BM=128 x BN=64 tile, BK=64, 256 threads (4 waves, 2x2), 16x16x32 bf16 MFMA.
// T2 XOR-swizzled LDS via pre-swizzled global source (global_load_lds writes
// linearly; source chunk s = p ^ (row&7), read slot p = s ^ (row&7)).
// ---------------------------------------------------------------------------
#define BM 128
#define BN 64
#define BK 64

#define GLOAD_LDS16(gp, lp)                                            \
    __builtin_amdgcn_global_load_lds(                                  \
        (const __attribute__((address_space(1))) void*)(gp),           \
        (__attribute__((address_space(3))) void*)(lp), 16, 0, 0)

__global__ __launch_bounds__(256) void gemm_dists_kernel(
        const u16* __restrict__ zb, const u16* __restrict__ mb,
        const float* __restrict__ z2, const float* __restrict__ m2,
        float* __restrict__ dists) {
    __shared__ u16 As[BM * BK];   // 16 KiB, swizzled [128][8 slots of 8 elems]
    __shared__ u16 Bs[BN * BK];   //  8 KiB

    const int tid  = threadIdx.x;
    const int wid  = tid >> 6;
    const int lane = tid & 63;
    const int wr   = wid >> 1;        // wave row 0..1 (64 rows each)
    const int wc   = wid & 1;         // wave col 0..1 (32 cols each)
    const int lrow = lane & 15;       // fragment row index
    const int kgrp = lane >> 4;       // k-group 0..3

    // T1: bijective XCD-chunked swizzle (nwg = 512, 512 % 8 == 0)
    const int nwg = gridDim.x * gridDim.y;
    const int bid = blockIdx.y * gridDim.x + blockIdx.x;
    const int swz = (bid & 7) * (nwg >> 3) + (bid >> 3);
    const int bxg = swz % gridDim.x;
    const int byg = swz / gridDim.x;

    const int brow = byg * BM;
    const int bcol = bxg * BN;

    f32x4 acc[4][2];
#pragma unroll
    for (int m = 0; m < 4; ++m)
#pragma unroll
        for (int n = 0; n < 2; ++n) acc[m][n] = (f32x4){0.f, 0.f, 0.f, 0.f};

    // Staging: chunk c (16B) -> physical (row = c>>3, slot p = c&7).
    // Physical slot p holds global k-slot s = p ^ (row&7) (XOR involution).
    const u16* gA[4];
    u16* lA[4];
#pragma unroll
    for (int g = 0; g < 4; ++g) {
        const int c = g * 256 + tid;
        const int r = c >> 3, p = c & 7, s = p ^ (r & 7);
        gA[g] = zb + (size_t)(brow + r) * ND + s * 8;
        lA[g] = As + (g * 256 + wid * 64) * 8;   // wave-uniform base
    }
    const u16* gB[2];
    u16* lB[2];
#pragma unroll
    for (int g = 0; g < 2; ++g) {
        const int c = g * 256 + tid;
        const int r = c >> 3, p = c & 7, s = p ^ (r & 7);
        gB[g] = mb + (size_t)(bcol + r) * ND + s * 8;
        lB[g] = Bs + (g * 256 + wid * 64) * 8;
    }

    const int lx = lrow & 7;          // row&7 for all fragment rows

    for (int k0 = 0; k0 < ND; k0 += BK) {
        __syncthreads();                 // prev iter's LDS reads done
#pragma unroll
        for (int g = 0; g < 4; ++g) GLOAD_LDS16(gA[g] + k0, lA[g]);
#pragma unroll
        for (int g = 0; g < 2; ++g) GLOAD_LDS16(gB[g] + k0, lB[g]);
        __syncthreads();                 // staging drained (vmcnt(0) at barrier)

#pragma unroll
        for (int ks = 0; ks < 2; ++ks) {
            const int pk = (ks * 4 + kgrp) ^ lx;   // swizzled 16B slot
            bf16x8 a[4], b[2];
#pragma unroll
            for (int m = 0; m < 4; ++m)
                a[m] = *(const bf16x8*)&As[(wr * 64 + m * 16 + lrow) * BK + pk * 8];
#pragma unroll
            for (int n = 0; n < 2; ++n)
                b[n] = *(const bf16x8*)&Bs[(wc * 32 + n * 16 + lrow) * BK + pk * 8];
#pragma unroll
            for (int m = 0; m < 4; ++m)
#pragma unroll
                for (int n = 0; n < 2; ++n)
                    acc[m][n] = __builtin_amdgcn_mfma_f32_16x16x32_bf16(
                        a[m], b[n], acc[m][n], 0, 0, 0);
        }
    }

    // epilogue: C/D layout col = lane&15, row = (lane>>4)*4 + r
#pragma unroll
    for (int n = 0; n < 2; ++n) {
        const int gcol = bcol + wc * 32 + n * 16 + lrow;
        const float mhalf = 0.5f * m2[gcol];
#pragma unroll
        for (int m = 0; m < 4; ++m) {
#pragma unroll
            for (int r = 0; r < 4; ++r) {
                const int grow = brow + wr * 64 + m * 16 + kgrp * 4 + r;
                dists[(size_t)grow * NCP + gcol] =
                    acc[m][n][r] - 0.5f * z2[grow] - mhalf;
            }
        }
    }
}

// ---------------------------------------------------------------------------
// Per-row logsumexp + picked: outA[b] = lse - dists[b,label], outB[b] = lse + sldj
// ---------------------------------------------------------------------------
__global__ __launch_bounds__(256) void row_lse_kernel(
        const float* __restrict__ dists, const int* __restrict__ labels,
        const float* __restrict__ sldj, float* __restrict__ outA,
        float* __restrict__ outB) {
    const int row = blockIdx.x;
    const int tid = threadIdx.x;
    const float* dr = dists + (size_t)row * NCP;
    float4 v = ((const float4*)dr)[tid];     // 256 * 4 = 1024 exactly

    float mx = fmaxf(fmaxf(v.x, v.y), fmaxf(v.z, v.w));
#pragma unroll
    for (int off = 32; off > 0; off >>= 1) mx = fmaxf(mx, __shfl_xor(mx, off, 64));
    __shared__ float smax[4], ssum[4];
    const int wid = tid >> 6, lane = tid & 63;
    if (lane == 0) smax[wid] = mx;
    __syncthreads();
    const float bm = fmaxf(fmaxf(smax[0], smax[1]), fmaxf(smax[2], smax[3]));

    float s = expf(v.x - bm) + expf(v.y - bm) + expf(v.z - bm) + expf(v.w - bm);
#pragma unroll
    for (int off = 32; off > 0; off >>= 1) s += __shfl_xor(s, off, 64);
    if (lane == 0) ssum[wid] = s;
    __syncthreads();
    if (tid == 0) {
        const float tot = ssum[0] + ssum[1] + ssum[2] + ssum[3];
        const float lpz = bm + logf(tot);
        const float picked = dr[labels[row]];
        outA[row] = lpz - picked;
        outB[row] = lpz + sldj[row];
    }
}

// ---------------------------------------------------------------------------
// Deterministic final reduction (single block, fixed tree order).
// ---------------------------------------------------------------------------
__global__ __launch_bounds__(1024) void finalize_kernel(
        const float* __restrict__ a, const float* __restrict__ b,
        const float* __restrict__ beta, float* __restrict__ out) {
    __shared__ float sa[1024], sb[1024];
    const int tid = threadIdx.x;
    float va = 0.f, vb = 0.f;
    for (int i = tid; i < NB; i += 1024) { va += a[i]; vb += b[i]; }
    sa[tid] = va; sb[tid] = vb;
    __syncthreads();
    for (int s = 512; s > 0; s >>= 1) {
        if (tid < s) { sa[tid] += sa[tid + s]; sb[tid] += sb[tid + s]; }
        __syncthreads();
    }
    if (tid == 0) {
        const float loss_cls = sa[0] / (float)NB;
        const float loss_gen = -(sb[0] / (float)NB) / (float)ND;
        const float total = loss_gen + beta[0] * loss_cls;
        out[0] = total;
        out[1] = loss_gen;
        out[2] = loss_cls;
    }
}

extern "C" void kernel_launch(void* const* d_in, const int* in_sizes, int n_in,
                              void* d_out, int out_size, void* d_ws, size_t ws_size,
                              hipStream_t stream) {
    const float* z      = (const float*)d_in[0];
    const float* sldj   = (const float*)d_in[1];
    const int*   labels = (const int*)d_in[2];
    const float* beta   = (const float*)d_in[3];
    const float* means  = (const float*)d_in[4];
    float* out = (float*)d_out;

    char* ws = (char*)d_ws;
    size_t off = 0;
    u16* zb = (u16*)(ws + off);      off += (size_t)NB * ND * 2;    // 25.2 MB
    u16* mb = (u16*)(ws + off);      off += (size_t)NCP * ND * 2;   //  6.3 MB
    float* z2 = (float*)(ws + off);  off += (size_t)NB * 4;
    float* m2 = (float*)(ws + off);  off += (size_t)NCP * 4;
    float* dists = (float*)(ws + off); off += (size_t)NB * NCP * 4; // 16.8 MB
    float* ra = (float*)(ws + off);  off += (size_t)NB * 4;
    float* rb = (float*)(ws + off);  off += (size_t)NB * 4;

    convert_rows_kernel<<<NB, 256, 0, stream>>>(z, zb, z2, NB, 0.f);
    convert_rows_kernel<<<NCP, 256, 0, stream>>>(means, mb, m2, NC, 1e30f);
    gemm_dists_kernel<<<dim3(NCP / BN, NB / BM), 256, 0, stream>>>(zb, mb, z2, m2, dists);
    row_lse_kernel<<<NB, 256, 0, stream>>>(dists, labels, sldj, ra, rb);
    finalize_kernel<<<1, 1024, 0, stream>>>(ra, rb, beta, out);
}